// Round 3
// baseline (1067.012 us; speedup 1.0000x reference)
//
#include <hip/hip_runtime.h>
#include <hip/hip_bf16.h>
#include <stdint.h>

#define NE 128
#define NI 1856
#define NKK 6
#define NH 512
#define NT 4096
#define CAP 320
#define NPAIR (NT*NKK)
#define LD2I (2*NI)

typedef unsigned short u16;
typedef __attribute__((ext_vector_type(4))) float f32x4;
typedef __attribute__((ext_vector_type(8))) short bf16x8;
typedef __attribute__((ext_vector_type(4))) short s16x4;
typedef const void __attribute__((address_space(1)))* gas1p;
typedef void __attribute__((address_space(3)))* gas3p;

__device__ __forceinline__ short f2bf(float f) {
  union { __hip_bfloat16 h; short s; } c; c.h = __float2bfloat16(f); return c.s;
}
__device__ __forceinline__ float bf2f(short s) {
  union { float f; unsigned u; } v; v.u = ((unsigned)(u16)s) << 16; return v.f;
}

// physical bid -> logical L such that consecutive L cluster on one XCD
// (hardware round-robins physical bids across 8 XCDs; bijective for any n)
__device__ __forceinline__ int xcd_logical(int bid, int n) {
  int q = n >> 3, r = n & 7;
  int xcd = bid & 7, j = bid >> 3;
  return xcd * q + (xcd < r ? xcd : r) + j;
}

// ---------------- routing ----------------
__global__ void k_route(const int* __restrict__ topk, int* __restrict__ counts,
                        int* __restrict__ slot_of_pair, int* __restrict__ pair_of_slot) {
  int n = blockIdx.x * 256 + threadIdx.x;
  if (n >= NPAIR) return;
  int e = topk[n];
  int p = atomicAdd(&counts[e], 1);
  int s = (p < CAP) ? e * CAP + p : -1;
  slot_of_pair[n] = s;
  if (s >= 0) pair_of_slot[s] = n;
}

// ---------------- gather: hidden(f32) -> Xbuf(bf16) ----------------
__global__ void k_gather(const float* __restrict__ hid, const int* __restrict__ counts,
                         const int* __restrict__ pair_of_slot, u16* __restrict__ xbuf) {
  int t = threadIdx.x;
  int row = blockIdx.x * 2 + (t >> 7);
  int c = t & 127;
  int e = row / CAP, p = row % CAP;
  if (p >= counts[e]) return;
  int n = pair_of_slot[row];
  int tok = n / NKK;
  f32x4 v = *(const f32x4*)(hid + (size_t)tok * NH + c * 4);
  s16x4 o;
  o[0] = f2bf(v[0]); o[1] = f2bf(v[1]); o[2] = f2bf(v[2]); o[3] = f2bf(v[3]);
  *(s16x4*)(xbuf + (size_t)row * NH + c * 4) = o;
}

// ---------------- GEMM1: X[rows,H] @ Wgu[H,2I] -> silu(g)*u -> inter(bf16) ----------------
// BM=256 (512 thr, 8 waves 4Mx2N), BN=64 inter-cols (64 gate + 64 up), BK=64
__global__ __launch_bounds__(512, 1) void k_gemm1(
    const u16* __restrict__ xbuf, const float* __restrict__ wgu,
    const int* __restrict__ counts, u16* __restrict__ inter, int e0, int nblk)
{
  __shared__ __align__(16) char lds[65536];
  int L = xcd_logical(blockIdx.x, nblk);
  int el = L / 58;
  int inner = L % 58;
  int nt = inner >> 1;
  int mt = inner & 1;
  int e = e0 + el;
  int cnt = counts[e];
  int row0 = mt * 256;
  if (row0 >= cnt) return;
  int n0 = nt * 64;
  int t = threadIdx.x, w = t >> 6, l = t & 63;
  int wm = w >> 1, wc = w & 1;
  const char* abase = (const char*)(xbuf + (size_t)e * CAP * NH);

  auto stage = [&](int buf, int kt) {
    char* dstb = lds + buf * 32768;
    #pragma unroll
    for (int i = 0; i < 4; ++i) {
      int seg = i * 8 + w;              // 0..31, 1KB each
      int o = seg * 1024 + l * 16;
      int r = o >> 7;
      int inr = o & 127;
      int si = inr ^ ((r & 7) << 4);
      int grow = row0 + r; grow = grow < CAP ? grow : CAP - 1;
      const char* g = abase + (size_t)grow * (NH * 2) + kt * 128 + si;
      __builtin_amdgcn_global_load_lds((gas1p)g, (gas3p)(dstb + seg * 1024), 16, 0, 0);
    }
  };

  f32x4 acc[4][4];
  #pragma unroll
  for (int m = 0; m < 4; ++m)
    #pragma unroll
    for (int b = 0; b < 4; ++b) acc[m][b] = (f32x4){0.f, 0.f, 0.f, 0.f};

  stage(0, 0);
  const float* wbase = wgu + (size_t)e * NH * LD2I + n0 + wc * 32 + (l & 15);

  for (int kt = 0; kt < 8; ++kt) {
    __syncthreads();
    if (kt + 1 < 8) stage((kt + 1) & 1, kt + 1);
    const char* abuf = lds + (kt & 1) * 32768;
    #pragma unroll
    for (int ks = 0; ks < 2; ++ks) {
      int krow = kt * 64 + ks * 32 + ((l >> 4) << 3);
      const float* bp = wbase + (size_t)krow * LD2I;
      float bv[4][8];
      #pragma unroll
      for (int nf = 0; nf < 2; ++nf)
        #pragma unroll
        for (int j = 0; j < 8; ++j) {
          bv[nf][j]     = bp[(size_t)j * LD2I + nf * 16];
          bv[2 + nf][j] = bp[(size_t)j * LD2I + nf * 16 + NI];
        }
      bf16x8 bfrag[4];
      #pragma unroll
      for (int b = 0; b < 4; ++b)
        #pragma unroll
        for (int j = 0; j < 8; ++j) bfrag[b][j] = f2bf(bv[b][j]);
      bf16x8 afrag[4];
      #pragma unroll
      for (int mf = 0; mf < 4; ++mf) {
        int r = wm * 64 + mf * 16 + (l & 15);
        int inr = (ks * 64 + ((l >> 4) << 4)) ^ ((r & 7) << 4);
        afrag[mf] = *(const bf16x8*)(abuf + r * 128 + inr);
      }
      #pragma unroll
      for (int mf = 0; mf < 4; ++mf)
        #pragma unroll
        for (int b = 0; b < 4; ++b)
          acc[mf][b] = __builtin_amdgcn_mfma_f32_16x16x32_bf16(afrag[mf], bfrag[b], acc[mf][b], 0, 0, 0);
    }
  }

  // last K-step's cross-wave ds_reads must finish before epilogue overwrites LDS
  __syncthreads();

  int vmax = cnt < CAP ? cnt : CAP;
  int rmax = vmax - row0; if (rmax > 256) rmax = 256;
  char* rb = lds;                        // 256 rows x 128B = 32KB
  #pragma unroll
  for (int mf = 0; mf < 4; ++mf)
    #pragma unroll
    for (int nf = 0; nf < 2; ++nf) {
      f32x4 g = acc[mf][nf], u = acc[mf][2 + nf];
      #pragma unroll
      for (int r = 0; r < 4; ++r) {
        float gv = g[r];
        float sv = gv / (1.f + __expf(-gv));
        float val = sv * u[r];
        int rl = wm * 64 + mf * 16 + ((l >> 4) << 2) + r;
        int cl = wc * 32 + nf * 16 + (l & 15);
        *(short*)(rb + rl * 128 + ((cl * 2) ^ ((rl & 7) << 4))) = f2bf(val);
      }
    }
  __syncthreads();
  u16* obase = inter + (size_t)(el * CAP + row0) * NI + n0;
  #pragma unroll
  for (int i = 0; i < 4; ++i) {
    int task = i * 512 + t;              // 2048 tasks = 256 rows x 8 parts
    int r = task >> 3, part = task & 7;
    if (r < rmax) {
      bf16x8 v = *(const bf16x8*)(rb + r * 128 + ((part * 16) ^ ((r & 7) << 4)));
      *(bf16x8*)(obase + (size_t)r * NI + part * 8) = v;
    }
  }
}

// ---------------- GEMM2: inter[rows,I] @ Wdn[I,H] -> Y(bf16) ----------------
__global__ __launch_bounds__(512, 1) void k_gemm2(
    const u16* __restrict__ inter, const float* __restrict__ wdn,
    const int* __restrict__ counts, u16* __restrict__ Y, int e0, int nblk)
{
  __shared__ __align__(16) char lds[65536];
  int L = xcd_logical(blockIdx.x, nblk);
  int el = L / 16;
  int inner = L % 16;
  int nt = inner >> 1;
  int mt = inner & 1;
  int e = e0 + el;
  int cnt = counts[e];
  int row0 = mt * 256;
  if (row0 >= cnt) return;
  int n0 = nt * 64;
  int t = threadIdx.x, w = t >> 6, l = t & 63;
  int wm = w >> 1, wc = w & 1;
  const char* abase = (const char*)(inter + (size_t)el * CAP * NI);

  auto stage = [&](int buf, int kt) {
    char* dstb = lds + buf * 32768;
    #pragma unroll
    for (int i = 0; i < 4; ++i) {
      int seg = i * 8 + w;
      int o = seg * 1024 + l * 16;
      int r = o >> 7;
      int inr = o & 127;
      int si = inr ^ ((r & 7) << 4);
      int grow = row0 + r; grow = grow < CAP ? grow : CAP - 1;
      const char* g = abase + (size_t)grow * (NI * 2) + kt * 128 + si;
      __builtin_amdgcn_global_load_lds((gas1p)g, (gas3p)(dstb + seg * 1024), 16, 0, 0);
    }
  };

  f32x4 acc[4][2];
  #pragma unroll
  for (int m = 0; m < 4; ++m) { acc[m][0] = (f32x4){0.f,0.f,0.f,0.f}; acc[m][1] = (f32x4){0.f,0.f,0.f,0.f}; }

  stage(0, 0);
  const float* wbase = wdn + (size_t)e * NI * NH + n0 + wc * 32 + (l & 15);

  for (int kt = 0; kt < 29; ++kt) {
    __syncthreads();
    if (kt + 1 < 29) stage((kt + 1) & 1, kt + 1);
    const char* abuf = lds + (kt & 1) * 32768;
    #pragma unroll
    for (int ks = 0; ks < 2; ++ks) {
      int krow = kt * 64 + ks * 32 + ((l >> 4) << 3);
      const float* bp = wbase + (size_t)krow * NH;
      float bv[2][8];
      #pragma unroll
      for (int nf = 0; nf < 2; ++nf)
        #pragma unroll
        for (int j = 0; j < 8; ++j) bv[nf][j] = bp[(size_t)j * NH + nf * 16];
      bf16x8 bfrag[2];
      #pragma unroll
      for (int b = 0; b < 2; ++b)
        #pragma unroll
        for (int j = 0; j < 8; ++j) bfrag[b][j] = f2bf(bv[b][j]);
      bf16x8 afrag[4];
      #pragma unroll
      for (int mf = 0; mf < 4; ++mf) {
        int r = wm * 64 + mf * 16 + (l & 15);
        int inr = (ks * 64 + ((l >> 4) << 4)) ^ ((r & 7) << 4);
        afrag[mf] = *(const bf16x8*)(abuf + r * 128 + inr);
      }
      #pragma unroll
      for (int mf = 0; mf < 4; ++mf)
        #pragma unroll
        for (int b = 0; b < 2; ++b)
          acc[mf][b] = __builtin_amdgcn_mfma_f32_16x16x32_bf16(afrag[mf], bfrag[b], acc[mf][b], 0, 0, 0);
    }
  }

  __syncthreads();

  int vmax = cnt < CAP ? cnt : CAP;
  int rmax = vmax - row0; if (rmax > 256) rmax = 256;
  char* rb = lds;
  #pragma unroll
  for (int mf = 0; mf < 4; ++mf)
    #pragma unroll
    for (int nf = 0; nf < 2; ++nf) {
      f32x4 a = acc[mf][nf];
      #pragma unroll
      for (int r = 0; r < 4; ++r) {
        int rl = wm * 64 + mf * 16 + ((l >> 4) << 2) + r;
        int cl = wc * 32 + nf * 16 + (l & 15);
        *(short*)(rb + rl * 128 + ((cl * 2) ^ ((rl & 7) << 4))) = f2bf(a[r]);
      }
    }
  __syncthreads();
  u16* obase = Y + (size_t)(e * CAP + row0) * NH + n0;
  #pragma unroll
  for (int i = 0; i < 4; ++i) {
    int task = i * 512 + t;
    int r = task >> 3, part = task & 7;
    if (r < rmax) {
      bf16x8 v = *(const bf16x8*)(rb + r * 128 + ((part * 16) ^ ((r & 7) << 4)));
      *(bf16x8*)(obase + (size_t)r * NH + part * 8) = v;
    }
  }
}

// ---------------- combine: out[t] = sum_k w * Y[slot] (both copies) ----------------
__global__ void k_combine(const int* __restrict__ slot_of_pair, const float* __restrict__ wts,
                          const u16* __restrict__ Y, float* __restrict__ out)
{
  int t = threadIdx.x;
  int tok = blockIdx.x * 2 + (t >> 7);
  int c = t & 127;
  f32x4 a = (f32x4){0.f, 0.f, 0.f, 0.f};
  #pragma unroll
  for (int k = 0; k < NKK; ++k) {
    int n = tok * NKK + k;
    int s = slot_of_pair[n];
    if (s >= 0) {
      float wv = wts[n];
      s16x4 y = *(const s16x4*)(Y + (size_t)s * NH + c * 4);
      a[0] += wv * bf2f(y[0]);
      a[1] += wv * bf2f(y[1]);
      a[2] += wv * bf2f(y[2]);
      a[3] += wv * bf2f(y[3]);
    }
  }
  *(f32x4*)(out + (size_t)tok * NH + c * 4) = a;
  *(f32x4*)(out + (size_t)(NT + tok) * NH + c * 4) = a;
}

extern "C" void kernel_launch(void* const* d_in, const int* in_sizes, int n_in,
                              void* d_out, int out_size, void* d_ws, size_t ws_size,
                              hipStream_t stream) {
  const float* hid  = (const float*)d_in[0];
  const int*   topk = (const int*)d_in[1];
  const float* wts  = (const float*)d_in[2];
  const float* wgu  = (const float*)d_in[3];
  const float* wdn  = (const float*)d_in[4];

  char* ws = (char*)d_ws;
  size_t off = 0;
  auto alloc = [&](size_t sz) { char* p = ws + off; off = (off + sz + 255) & ~(size_t)255; return p; };
  int* counts        = (int*)alloc(NE * 4);
  int* slot_of_pair  = (int*)alloc((size_t)NPAIR * 4);
  int* pair_of_slot  = (int*)alloc((size_t)NE * CAP * 4);
  u16* xbuf          = (u16*)alloc((size_t)NE * CAP * NH * 2);
  u16* Y             = (u16*)alloc((size_t)NE * CAP * NH * 2);
  size_t remain = ws_size > off ? ws_size - off : 0;
  size_t per_e = (size_t)CAP * NI * 2;
  int chunkE = (int)(remain / per_e);
  if (chunkE > NE) chunkE = NE;
  if (chunkE < 1) chunkE = 1;
  u16* inter = (u16*)(ws + off);

  hipMemsetAsync(counts, 0, NE * 4, stream);
  k_route<<<NPAIR / 256, 256, 0, stream>>>(topk, counts, slot_of_pair, pair_of_slot);
  k_gather<<<NE * CAP / 2, 256, 0, stream>>>(hid, counts, pair_of_slot, xbuf);
  for (int e0 = 0; e0 < NE; e0 += chunkE) {
    int ce = NE - e0 < chunkE ? NE - e0 : chunkE;
    int nb1 = ce * 58;   // 29 nt x 2 mt
    int nb2 = ce * 16;   // 8 nt x 2 mt
    k_gemm1<<<nb1, 512, 0, stream>>>(xbuf, wgu, counts, inter, e0, nb1);
    k_gemm2<<<nb2, 512, 0, stream>>>(inter, wdn, counts, Y, e0, nb2);
  }
  k_combine<<<NT / 2, 256, 0, stream>>>(slot_of_pair, wts, Y, (float*)d_out);
}

// Round 4
// 642.459 us; speedup vs baseline: 1.6608x; 1.6608x over previous
//
#include <hip/hip_runtime.h>
#include <hip/hip_bf16.h>
#include <stdint.h>

#define NE 128
#define NI 1856
#define NKK 6
#define NH 512
#define NT 4096
#define CAP 320
#define NPAIR (NT*NKK)
#define LD2I (2*NI)

typedef unsigned short u16;
typedef __attribute__((ext_vector_type(4))) float f32x4;
typedef __attribute__((ext_vector_type(8))) short bf16x8;
typedef __attribute__((ext_vector_type(4))) short s16x4;
typedef const void __attribute__((address_space(1)))* gas1p;
typedef void __attribute__((address_space(3)))* gas3p;

__device__ __forceinline__ short f2bf(float f) {
  union { __hip_bfloat16 h; short s; } c; c.h = __float2bfloat16(f); return c.s;
}
__device__ __forceinline__ float bf2f(short s) {
  union { float f; unsigned u; } v; v.u = ((unsigned)(u16)s) << 16; return v.f;
}

// physical bid -> logical L clustering consecutive L on one XCD (bijective any n)
__device__ __forceinline__ int xcd_logical(int bid, int n) {
  int q = n >> 3, r = n & 7;
  int xcd = bid & 7, j = bid >> 3;
  return xcd * q + (xcd < r ? xcd : r) + j;
}

// ---------------- routing ----------------
__global__ void k_route(const int* __restrict__ topk, int* __restrict__ counts,
                        int* __restrict__ slot_of_pair, int* __restrict__ pair_of_slot) {
  int n = blockIdx.x * 256 + threadIdx.x;
  if (n >= NPAIR) return;
  int e = topk[n];
  int p = atomicAdd(&counts[e], 1);
  int s = (p < CAP) ? e * CAP + p : -1;
  slot_of_pair[n] = s;
  if (s >= 0) pair_of_slot[s] = n;
}

// ---------------- gather: hidden(f32) -> Xbuf(bf16) ----------------
__global__ void k_gather(const float* __restrict__ hid, const int* __restrict__ counts,
                         const int* __restrict__ pair_of_slot, u16* __restrict__ xbuf) {
  int t = threadIdx.x;
  int row = blockIdx.x * 2 + (t >> 7);
  int c = t & 127;
  int e = row / CAP, p = row % CAP;
  if (p >= counts[e]) return;
  int n = pair_of_slot[row];
  int tok = n / NKK;
  f32x4 v = *(const f32x4*)(hid + (size_t)tok * NH + c * 4);
  s16x4 o;
  o[0] = f2bf(v[0]); o[1] = f2bf(v[1]); o[2] = f2bf(v[2]); o[3] = f2bf(v[3]);
  *(s16x4*)(xbuf + (size_t)row * NH + c * 4) = o;
}

// ---------------- GEMM1: X[256,H]@Wgu[H, 32g+32u] -> silu*up -> inter ----------------
// 256 thr (4 waves 2Mx2N), BM=256 (2 mt in-reg), BN_inter=32, BK=32, LDS 40KB
__global__ __launch_bounds__(256, 3) void k_gemm1(
    const u16* __restrict__ xbuf, const float* __restrict__ wgu,
    const int* __restrict__ counts, u16* __restrict__ inter, int e0, int nblk)
{
  __shared__ __align__(16) char lds[40960];   // A: 2x16KB @0, B: 2x4KB @32768
  int L = xcd_logical(blockIdx.x, nblk);
  int el = L / 58, nt = L % 58;
  int e = e0 + el;
  int cnt = counts[e]; if (cnt > CAP) cnt = CAP;
  int n0 = nt * 32;
  int t = threadIdx.x, w = t >> 6, l = t & 63;
  int wm = w >> 1, wc = w & 1;
  const char* abase = (const char*)(xbuf + (size_t)e * CAP * NH);

  // B staging role: thread -> (col 0..63, kchunk 0..3)
  int bc = t & 63, bkc = t >> 6;
  int gcol = (bc < 32) ? (n0 + bc) : (NI + n0 + (bc - 32));
  const float* bsrc = wgu + (size_t)e * NH * LD2I + gcol;
  float bv[8];

  int kg16 = (l >> 4) * 16;          // k byte offset of this lane's frag group
  int bcol0 = wc * 16 + (l & 15);    // gate col in B_lds
  int bswz = ((bcol0 & 3) << 4);

  for (int base = 0; base < cnt; base += 256) {
    __syncthreads();   // protect repack region (bufA0) reuse on base wrap

    auto stageA = [&](int buf, int kt) {
      char* dstb = lds + buf * 16384;
      #pragma unroll
      for (int i = 0; i < 4; ++i) {
        int seg = i * 4 + w;                 // 0..15 (1KB each)
        int o = seg * 1024 + l * 16;
        int r = o >> 6, slot = o & 63;
        int grow = base + r; if (grow > CAP - 1) grow = CAP - 1;
        const char* g = abase + (size_t)grow * (NH * 2) + kt * 64 + (slot ^ ((r & 3) << 4));
        __builtin_amdgcn_global_load_lds((gas1p)g, (gas3p)(dstb + seg * 1024), 16, 0, 0);
      }
    };
    auto loadB = [&](int kt) {
      const float* p = bsrc + (size_t)(kt * 32 + bkc * 8) * LD2I;
      #pragma unroll
      for (int j = 0; j < 8; ++j) bv[j] = p[(size_t)j * LD2I];
    };
    auto writeB = [&](int buf) {
      bf16x8 o;
      #pragma unroll
      for (int j = 0; j < 8; ++j) o[j] = f2bf(bv[j]);
      char* bb = lds + 32768 + buf * 4096;
      *(bf16x8*)(bb + bc * 64 + ((bkc * 16) ^ ((bc & 3) << 4))) = o;
    };

    f32x4 acc[2][4][2];
    #pragma unroll
    for (int m = 0; m < 2; ++m)
      #pragma unroll
      for (int f = 0; f < 4; ++f) { acc[m][f][0] = (f32x4){0,0,0,0}; acc[m][f][1] = (f32x4){0,0,0,0}; }

    loadB(0);
    stageA(0, 0);
    writeB(0);

    for (int kt = 0; kt < 16; ++kt) {
      __syncthreads();
      int cur = kt & 1, nxt = cur ^ 1;
      if (kt + 1 < 16) { loadB(kt + 1); stageA(nxt, kt + 1); }
      const char* ab = lds + cur * 16384;
      const char* bb = lds + 32768 + cur * 4096;
      bf16x8 bg = *(const bf16x8*)(bb + bcol0 * 64 + (kg16 ^ bswz));
      bf16x8 bu = *(const bf16x8*)(bb + (32 + bcol0) * 64 + (kg16 ^ bswz));
      #pragma unroll
      for (int mt = 0; mt < 2; ++mt)
        #pragma unroll
        for (int mf = 0; mf < 4; ++mf) {
          int r = mt * 128 + wm * 64 + mf * 16 + (l & 15);
          bf16x8 af = *(const bf16x8*)(ab + r * 64 + (kg16 ^ ((r & 3) << 4)));
          acc[mt][mf][0] = __builtin_amdgcn_mfma_f32_16x16x32_bf16(af, bg, acc[mt][mf][0], 0, 0, 0);
          acc[mt][mf][1] = __builtin_amdgcn_mfma_f32_16x16x32_bf16(af, bu, acc[mt][mf][1], 0, 0, 0);
        }
      if (kt + 1 < 16) writeB(nxt);
    }

    __syncthreads();   // all frag reads done before repack overwrites bufA0

    // epilogue: silu(g)*u -> repack rows x 64B -> coalesced stores
    int cl = wc * 16 + (l & 15);
    #pragma unroll
    for (int mt = 0; mt < 2; ++mt)
      #pragma unroll
      for (int mf = 0; mf < 4; ++mf) {
        f32x4 g = acc[mt][mf][0], u = acc[mt][mf][1];
        #pragma unroll
        for (int r = 0; r < 4; ++r) {
          float gv = g[r];
          float val = gv / (1.f + __expf(-gv)) * u[r];
          int rl = mt * 128 + wm * 64 + mf * 16 + (l >> 4) * 4 + r;
          *(short*)(lds + rl * 64 + ((cl * 2) ^ ((rl & 3) << 4))) = f2bf(val);
        }
      }
    __syncthreads();
    int rmax = cnt - base; if (rmax > 256) rmax = 256;
    u16* obase = inter + (size_t)(el * CAP + base) * NI + n0;
    #pragma unroll
    for (int i = 0; i < 4; ++i) {
      int task = i * 256 + t;
      int r = task >> 2, p = task & 3;
      if (r < rmax) {
        bf16x8 v = *(const bf16x8*)(lds + r * 64 + ((p * 16) ^ ((r & 3) << 4)));
        *(bf16x8*)(obase + (size_t)r * NI + p * 8) = v;
      }
    }
  }
}

// ---------------- GEMM2: inter[256,I]@Wdn[I,64] -> Y ----------------
// 256 thr, BM=256 (2 mt), BN=64, BK=32, KT=58, LDS 40KB
__global__ __launch_bounds__(256, 3) void k_gemm2(
    const u16* __restrict__ inter, const float* __restrict__ wdn,
    const int* __restrict__ counts, u16* __restrict__ Y, int e0, int nblk)
{
  __shared__ __align__(16) char lds[40960];
  int L = xcd_logical(blockIdx.x, nblk);
  int el = L / 8, nt = L % 8;
  int e = e0 + el;
  int cnt = counts[e]; if (cnt > CAP) cnt = CAP;
  int n0 = nt * 64;
  int t = threadIdx.x, w = t >> 6, l = t & 63;
  int wm = w >> 1, wc = w & 1;
  const char* abase = (const char*)(inter + (size_t)el * CAP * NI);

  int bc = t & 63, bkc = t >> 6;
  const float* bsrc = wdn + (size_t)e * NI * NH + n0 + bc;
  float bv[8];

  int kg16 = (l >> 4) * 16;
  int bcol0 = wc * 32 + (l & 15);     // frag0 col; frag1 = +16
  int bswz = ((bcol0 & 3) << 4);

  for (int base = 0; base < cnt; base += 256) {
    __syncthreads();

    auto stageA = [&](int buf, int kt) {
      char* dstb = lds + buf * 16384;
      #pragma unroll
      for (int i = 0; i < 4; ++i) {
        int seg = i * 4 + w;
        int o = seg * 1024 + l * 16;
        int r = o >> 6, slot = o & 63;
        int grow = base + r; if (grow > CAP - 1) grow = CAP - 1;
        const char* g = abase + (size_t)grow * (NI * 2) + kt * 64 + (slot ^ ((r & 3) << 4));
        __builtin_amdgcn_global_load_lds((gas1p)g, (gas3p)(dstb + seg * 1024), 16, 0, 0);
      }
    };
    auto loadB = [&](int kt) {
      const float* p = bsrc + (size_t)(kt * 32 + bkc * 8) * NH;
      #pragma unroll
      for (int j = 0; j < 8; ++j) bv[j] = p[(size_t)j * NH];
    };
    auto writeB = [&](int buf) {
      bf16x8 o;
      #pragma unroll
      for (int j = 0; j < 8; ++j) o[j] = f2bf(bv[j]);
      char* bb = lds + 32768 + buf * 4096;
      *(bf16x8*)(bb + bc * 64 + ((bkc * 16) ^ ((bc & 3) << 4))) = o;
    };

    f32x4 acc[2][4][2];
    #pragma unroll
    for (int m = 0; m < 2; ++m)
      #pragma unroll
      for (int f = 0; f < 4; ++f) { acc[m][f][0] = (f32x4){0,0,0,0}; acc[m][f][1] = (f32x4){0,0,0,0}; }

    loadB(0);
    stageA(0, 0);
    writeB(0);

    for (int kt = 0; kt < 58; ++kt) {
      __syncthreads();
      int cur = kt & 1, nxt = cur ^ 1;
      if (kt + 1 < 58) { loadB(kt + 1); stageA(nxt, kt + 1); }
      const char* ab = lds + cur * 16384;
      const char* bb = lds + 32768 + cur * 4096;
      bf16x8 b0 = *(const bf16x8*)(bb + bcol0 * 64 + (kg16 ^ bswz));
      bf16x8 b1 = *(const bf16x8*)(bb + (16 + bcol0) * 64 + (kg16 ^ bswz));
      #pragma unroll
      for (int mt = 0; mt < 2; ++mt)
        #pragma unroll
        for (int mf = 0; mf < 4; ++mf) {
          int r = mt * 128 + wm * 64 + mf * 16 + (l & 15);
          bf16x8 af = *(const bf16x8*)(ab + r * 64 + (kg16 ^ ((r & 3) << 4)));
          acc[mt][mf][0] = __builtin_amdgcn_mfma_f32_16x16x32_bf16(af, b0, acc[mt][mf][0], 0, 0, 0);
          acc[mt][mf][1] = __builtin_amdgcn_mfma_f32_16x16x32_bf16(af, b1, acc[mt][mf][1], 0, 0, 0);
        }
      if (kt + 1 < 58) writeB(nxt);
    }

    __syncthreads();

    // repack: 256 rows x 128B (64 cols bf16)
    #pragma unroll
    for (int mt = 0; mt < 2; ++mt)
      #pragma unroll
      for (int mf = 0; mf < 4; ++mf)
        #pragma unroll
        for (int f = 0; f < 2; ++f) {
          f32x4 a = acc[mt][mf][f];
          int cl = wc * 32 + f * 16 + (l & 15);
          #pragma unroll
          for (int r = 0; r < 4; ++r) {
            int rl = mt * 128 + wm * 64 + mf * 16 + (l >> 4) * 4 + r;
            *(short*)(lds + rl * 128 + ((cl * 2) ^ ((rl & 7) << 4))) = f2bf(a[r]);
          }
        }
    __syncthreads();
    int rmax = cnt - base; if (rmax > 256) rmax = 256;
    u16* obase = Y + (size_t)(e * CAP + base) * NH + n0;
    #pragma unroll
    for (int i = 0; i < 8; ++i) {
      int task = i * 256 + t;
      int r = task >> 3, p = task & 7;
      if (r < rmax) {
        bf16x8 v = *(const bf16x8*)(lds + r * 128 + ((p * 16) ^ ((r & 7) << 4)));
        *(bf16x8*)(obase + (size_t)r * NH + p * 8) = v;
      }
    }
  }
}

// ---------------- combine ----------------
__global__ void k_combine(const int* __restrict__ slot_of_pair, const float* __restrict__ wts,
                          const u16* __restrict__ Y, float* __restrict__ out)
{
  int t = threadIdx.x;
  int tok = blockIdx.x * 2 + (t >> 7);
  int c = t & 127;
  f32x4 a = (f32x4){0.f, 0.f, 0.f, 0.f};
  #pragma unroll
  for (int k = 0; k < NKK; ++k) {
    int n = tok * NKK + k;
    int s = slot_of_pair[n];
    if (s >= 0) {
      float wv = wts[n];
      s16x4 y = *(const s16x4*)(Y + (size_t)s * NH + c * 4);
      a[0] += wv * bf2f(y[0]);
      a[1] += wv * bf2f(y[1]);
      a[2] += wv * bf2f(y[2]);
      a[3] += wv * bf2f(y[3]);
    }
  }
  *(f32x4*)(out + (size_t)tok * NH + c * 4) = a;
  *(f32x4*)(out + (size_t)(NT + tok) * NH + c * 4) = a;
}

extern "C" void kernel_launch(void* const* d_in, const int* in_sizes, int n_in,
                              void* d_out, int out_size, void* d_ws, size_t ws_size,
                              hipStream_t stream) {
  const float* hid  = (const float*)d_in[0];
  const int*   topk = (const int*)d_in[1];
  const float* wts  = (const float*)d_in[2];
  const float* wgu  = (const float*)d_in[3];
  const float* wdn  = (const float*)d_in[4];

  char* ws = (char*)d_ws;
  size_t off = 0;
  auto alloc = [&](size_t sz) { char* p = ws + off; off = (off + sz + 255) & ~(size_t)255; return p; };
  int* counts        = (int*)alloc(NE * 4);
  int* slot_of_pair  = (int*)alloc((size_t)NPAIR * 4);
  int* pair_of_slot  = (int*)alloc((size_t)NE * CAP * 4);
  u16* xbuf          = (u16*)alloc((size_t)NE * CAP * NH * 2);
  u16* Y             = (u16*)alloc((size_t)NE * CAP * NH * 2);
  size_t remain = ws_size > off ? ws_size - off : 0;
  size_t per_e = (size_t)CAP * NI * 2;
  int chunkE = (int)(remain / per_e);
  if (chunkE > NE) chunkE = NE;
  if (chunkE < 1) chunkE = 1;
  u16* inter = (u16*)(ws + off);

  hipMemsetAsync(counts, 0, NE * 4, stream);
  k_route<<<NPAIR / 256, 256, 0, stream>>>(topk, counts, slot_of_pair, pair_of_slot);
  k_gather<<<NE * CAP / 2, 256, 0, stream>>>(hid, counts, pair_of_slot, xbuf);
  for (int e0 = 0; e0 < NE; e0 += chunkE) {
    int ce = NE - e0 < chunkE ? NE - e0 : chunkE;
    int nb1 = ce * 58;
    int nb2 = ce * 8;
    k_gemm1<<<nb1, 256, 0, stream>>>(xbuf, wgu, counts, inter, e0, nb1);
    k_gemm2<<<nb2, 256, 0, stream>>>(inter, wdn, counts, Y, e0, nb2);
  }
  k_combine<<<NT / 2, 256, 0, stream>>>(slot_of_pair, wts, Y, (float*)d_out);
}

// Round 6
// 534.476 us; speedup vs baseline: 1.9964x; 1.2020x over previous
//
#include <hip/hip_runtime.h>
#include <hip/hip_bf16.h>
#include <stdint.h>

#define NE 128
#define NI 1856
#define NKK 6
#define NH 512
#define NT 4096
#define CAP 320
#define NPAIR (NT*NKK)
#define LD2I (2*NI)

typedef unsigned short u16;
typedef __attribute__((ext_vector_type(4))) float f32x4;
typedef __attribute__((ext_vector_type(8))) short bf16x8;
typedef __attribute__((ext_vector_type(4))) short s16x4;
typedef const void __attribute__((address_space(1)))* gas1p;
typedef void __attribute__((address_space(3)))* gas3p;

#define SFENCE __builtin_amdgcn_sched_barrier(0)

__device__ __forceinline__ short f2bf(float f) {
  union { __hip_bfloat16 h; short s; } c; c.h = __float2bfloat16(f); return c.s;
}
__device__ __forceinline__ float bf2f(short s) {
  union { float f; unsigned u; } v; v.u = ((unsigned)(u16)s) << 16; return v.f;
}

// physical bid -> logical L clustering consecutive L on one XCD (bijective any n)
__device__ __forceinline__ int xcd_logical(int bid, int n) {
  int q = n >> 3, r = n & 7;
  int xcd = bid & 7, j = bid >> 3;
  return xcd * q + (xcd < r ? xcd : r) + j;
}

// ---------------- routing ----------------
__global__ void k_route(const int* __restrict__ topk, int* __restrict__ counts,
                        int* __restrict__ slot_of_pair, int* __restrict__ pair_of_slot) {
  int n = blockIdx.x * 256 + threadIdx.x;
  if (n >= NPAIR) return;
  int e = topk[n];
  int p = atomicAdd(&counts[e], 1);
  int s = (p < CAP) ? e * CAP + p : -1;
  slot_of_pair[n] = s;
  if (s >= 0) pair_of_slot[s] = n;
}

// ---------------- gather: hidden(f32) -> Xbuf(bf16) ----------------
__global__ void k_gather(const float* __restrict__ hid, const int* __restrict__ counts,
                         const int* __restrict__ pair_of_slot, u16* __restrict__ xbuf) {
  int t = threadIdx.x;
  int row = blockIdx.x * 2 + (t >> 7);
  int c = t & 127;
  int e = row / CAP, p = row % CAP;
  if (p >= counts[e]) return;
  int n = pair_of_slot[row];
  int tok = n / NKK;
  f32x4 v = *(const f32x4*)(hid + (size_t)tok * NH + c * 4);
  s16x4 o;
  o[0] = f2bf(v[0]); o[1] = f2bf(v[1]); o[2] = f2bf(v[2]); o[3] = f2bf(v[3]);
  *(s16x4*)(xbuf + (size_t)row * NH + c * 4) = o;
}

// ======================= GEMM1 =======================
// X[<=256,512]bf16 @ Wgu[512, 32gate+32up]f32 -> silu*up -> inter bf16
// 256 thr (4 waves 2Mx2N), BK=32, KT=16. All staging via global_load_lds:
// per wave per K-iter exactly 6 ops (4 A + 2 B-f32), triple buffer, stage X+2,
// end-of-iter s_waitcnt vmcnt(6) (drains X+1, leaves X+2 in flight).
__global__ __launch_bounds__(256, 2) void k_gemm1(
    const u16* __restrict__ xbuf, const float* __restrict__ wgu,
    const int* __restrict__ counts, u16* __restrict__ inter, int e0, int nblk)
{
  __shared__ __align__(16) char lds[73728];   // A: 3x16384 @0; B(f32): 3x8192 @49152
  int L = xcd_logical(blockIdx.x, nblk);
  int el = L / 58, nt = L % 58;
  int e = e0 + el;
  int cnt = counts[e]; if (cnt > CAP) cnt = CAP;
  int n0 = nt * 32;
  int t = threadIdx.x, w = t >> 6, l = t & 63;
  int wm = w >> 1, wc = w & 1;
  const char* abase = (const char*)(xbuf + (size_t)e * CAP * NH);

  // B stage: per-lane global src; LDS dest is wave-uniform (HW adds lane*16)
  int bks = l >> 4;               // k sub-row 0..3 within a 4-row segment
  int c4 = (l & 15) * 4;          // col chunk (4 f32)
  int gcol = (c4 < 32) ? (n0 + c4) : (NI + n0 + (c4 - 32));
  const float* bsrc = wgu + (size_t)e * NH * LD2I + gcol;

  // fragment-read params
  int kg = l >> 4;                // k-group 0..3 (8 k each)
  int kg16 = kg * 16;             // byte offset in A rows
  int colg = wc * 16 + (l & 15);  // gate col 0..31 (up = +32)

  for (int base = 0; base < cnt; base += 256) {
    __syncthreads();

    auto STAGE = [&](int buf, int kt) {
      char* ad = lds + buf * 16384;
      #pragma unroll
      for (int i = 0; i < 4; ++i) {
        int seg = i * 4 + w;
        int o = seg * 1024 + l * 16;
        int r = o >> 6, slot = o & 63;
        int grow = base + r; if (grow > CAP - 1) grow = CAP - 1;
        const char* g = abase + (size_t)grow * (NH * 2) + kt * 64 + (slot ^ ((r & 3) << 4));
        __builtin_amdgcn_global_load_lds((gas1p)g, (gas3p)(ad + seg * 1024), 16, 0, 0);
      }
      char* bd = lds + 49152 + buf * 8192;
      #pragma unroll
      for (int i = 0; i < 2; ++i) {
        int seg = w * 2 + i;                       // 0..7 (4 k-rows each)
        int k = seg * 4 + bks;                     // 0..31
        const char* g = (const char*)(bsrc + (size_t)(kt * 32 + k) * LD2I);
        __builtin_amdgcn_global_load_lds((gas1p)g, (gas3p)(bd + seg * 1024), 16, 0, 0);
      }
    };

    f32x4 acc[2][4][2];
    #pragma unroll
    for (int m = 0; m < 2; ++m)
      #pragma unroll
      for (int f = 0; f < 4; ++f) { acc[m][f][0] = (f32x4){0,0,0,0}; acc[m][f][1] = (f32x4){0,0,0,0}; }

    STAGE(0, 0);
    STAGE(1, 1);
    SFENCE; asm volatile("s_waitcnt vmcnt(6) lgkmcnt(0)" ::: "memory"); SFENCE;

    for (int kt = 0; kt < 16; ++kt) {
      SFENCE; __builtin_amdgcn_s_barrier(); SFENCE;
      int sk = (kt + 2 < 16) ? kt + 2 : 15;
      STAGE((kt + 2) % 3, sk);

      const char* ab = lds + (kt % 3) * 16384;
      const char* bb = lds + 49152 + (kt % 3) * 8192;
      bf16x8 bg, bu;
      #pragma unroll
      for (int j = 0; j < 8; ++j) {
        int k = kg * 8 + j;
        bg[j] = f2bf(*(const float*)(bb + k * 256 + colg * 4));
        bu[j] = f2bf(*(const float*)(bb + k * 256 + (colg + 32) * 4));
      }
      #pragma unroll
      for (int mt = 0; mt < 2; ++mt)
        #pragma unroll
        for (int mf = 0; mf < 4; ++mf) {
          int r = mt * 128 + wm * 64 + mf * 16 + (l & 15);
          bf16x8 af = *(const bf16x8*)(ab + r * 64 + (kg16 ^ ((r & 3) << 4)));
          acc[mt][mf][0] = __builtin_amdgcn_mfma_f32_16x16x32_bf16(af, bg, acc[mt][mf][0], 0, 0, 0);
          acc[mt][mf][1] = __builtin_amdgcn_mfma_f32_16x16x32_bf16(af, bu, acc[mt][mf][1], 0, 0, 0);
        }
      SFENCE; asm volatile("s_waitcnt vmcnt(6) lgkmcnt(0)" ::: "memory"); SFENCE;
    }
    __syncthreads();   // full drain; all frag reads done before LDS reuse

    // epilogue: silu(g)*u -> repack rows x 64B -> coalesced stores
    int cl = wc * 16 + (l & 15);
    #pragma unroll
    for (int mt = 0; mt < 2; ++mt)
      #pragma unroll
      for (int mf = 0; mf < 4; ++mf) {
        f32x4 g = acc[mt][mf][0], u = acc[mt][mf][1];
        #pragma unroll
        for (int r = 0; r < 4; ++r) {
          float gv = g[r];
          float val = gv / (1.f + __expf(-gv)) * u[r];
          int rl = mt * 128 + wm * 64 + mf * 16 + (l >> 4) * 4 + r;
          *(short*)(lds + rl * 64 + ((cl * 2) ^ ((rl & 3) << 4))) = f2bf(val);
        }
      }
    __syncthreads();
    int rmax = cnt - base; if (rmax > 256) rmax = 256;
    u16* obase = inter + (size_t)(el * CAP + base) * NI + n0;
    #pragma unroll
    for (int i = 0; i < 4; ++i) {
      int task = i * 256 + t;
      int r = task >> 2, p = task & 3;
      if (r < rmax) {
        bf16x8 v = *(const bf16x8*)(lds + r * 64 + ((p * 16) ^ ((r & 3) << 4)));
        *(bf16x8*)(obase + (size_t)r * NI + p * 8) = v;
      }
    }
  }
}

// ======================= GEMM2 =======================
// inter[<=256,1856]bf16 @ Wdn[1856,64]f32 -> Y bf16; KT=58, same pipeline
__global__ __launch_bounds__(256, 2) void k_gemm2(
    const u16* __restrict__ inter, const float* __restrict__ wdn,
    const int* __restrict__ counts, u16* __restrict__ Y, int e0, int nblk)
{
  __shared__ __align__(16) char lds[73728];
  int L = xcd_logical(blockIdx.x, nblk);
  int el = L / 8, nt = L % 8;
  int e = e0 + el;
  int cnt = counts[e]; if (cnt > CAP) cnt = CAP;
  int n0 = nt * 64;
  int t = threadIdx.x, w = t >> 6, l = t & 63;
  int wm = w >> 1, wc = w & 1;
  const char* abase = (const char*)(inter + (size_t)el * CAP * NI);

  int bks = l >> 4;
  int c4 = (l & 15) * 4;
  const float* bsrc = wdn + (size_t)e * NI * NH + n0 + c4;

  int kg = l >> 4;
  int kg16 = kg * 16;
  int col0 = wc * 32 + (l & 15);   // frag0 col; frag1 = +16

  for (int base = 0; base < cnt; base += 256) {
    __syncthreads();

    auto STAGE = [&](int buf, int kt) {
      char* ad = lds + buf * 16384;
      #pragma unroll
      for (int i = 0; i < 4; ++i) {
        int seg = i * 4 + w;
        int o = seg * 1024 + l * 16;
        int r = o >> 6, slot = o & 63;
        int grow = base + r; if (grow > CAP - 1) grow = CAP - 1;
        const char* g = abase + (size_t)grow * (NI * 2) + kt * 64 + (slot ^ ((r & 3) << 4));
        __builtin_amdgcn_global_load_lds((gas1p)g, (gas3p)(ad + seg * 1024), 16, 0, 0);
      }
      char* bd = lds + 49152 + buf * 8192;
      #pragma unroll
      for (int i = 0; i < 2; ++i) {
        int seg = w * 2 + i;
        int k = seg * 4 + bks;
        const char* g = (const char*)(bsrc + (size_t)(kt * 32 + k) * NH);
        __builtin_amdgcn_global_load_lds((gas1p)g, (gas3p)(bd + seg * 1024), 16, 0, 0);
      }
    };

    f32x4 acc[2][4][2];
    #pragma unroll
    for (int m = 0; m < 2; ++m)
      #pragma unroll
      for (int f = 0; f < 4; ++f) { acc[m][f][0] = (f32x4){0,0,0,0}; acc[m][f][1] = (f32x4){0,0,0,0}; }

    STAGE(0, 0);
    STAGE(1, 1);
    SFENCE; asm volatile("s_waitcnt vmcnt(6) lgkmcnt(0)" ::: "memory"); SFENCE;

    for (int kt = 0; kt < 58; ++kt) {
      SFENCE; __builtin_amdgcn_s_barrier(); SFENCE;
      int sk = (kt + 2 < 58) ? kt + 2 : 57;
      STAGE((kt + 2) % 3, sk);

      const char* ab = lds + (kt % 3) * 16384;
      const char* bb = lds + 49152 + (kt % 3) * 8192;
      bf16x8 b0, b1;
      #pragma unroll
      for (int j = 0; j < 8; ++j) {
        int k = kg * 8 + j;
        b0[j] = f2bf(*(const float*)(bb + k * 256 + col0 * 4));
        b1[j] = f2bf(*(const float*)(bb + k * 256 + (col0 + 16) * 4));
      }
      #pragma unroll
      for (int mt = 0; mt < 2; ++mt)
        #pragma unroll
        for (int mf = 0; mf < 4; ++mf) {
          int r = mt * 128 + wm * 64 + mf * 16 + (l & 15);
          bf16x8 af = *(const bf16x8*)(ab + r * 64 + (kg16 ^ ((r & 3) << 4)));
          acc[mt][mf][0] = __builtin_amdgcn_mfma_f32_16x16x32_bf16(af, b0, acc[mt][mf][0], 0, 0, 0);
          acc[mt][mf][1] = __builtin_amdgcn_mfma_f32_16x16x32_bf16(af, b1, acc[mt][mf][1], 0, 0, 0);
        }
      SFENCE; asm volatile("s_waitcnt vmcnt(6) lgkmcnt(0)" ::: "memory"); SFENCE;
    }
    __syncthreads();

    // repack: 256 rows x 128B (64 cols bf16)
    #pragma unroll
    for (int mt = 0; mt < 2; ++mt)
      #pragma unroll
      for (int mf = 0; mf < 4; ++mf)
        #pragma unroll
        for (int f = 0; f < 2; ++f) {
          f32x4 a = acc[mt][mf][f];
          int cl = wc * 32 + f * 16 + (l & 15);
          #pragma unroll
          for (int r = 0; r < 4; ++r) {
            int rl = mt * 128 + wm * 64 + mf * 16 + (l >> 4) * 4 + r;
            *(short*)(lds + rl * 128 + ((cl * 2) ^ ((rl & 7) << 4))) = f2bf(a[r]);
          }
        }
    __syncthreads();
    int rmax = cnt - base; if (rmax > 256) rmax = 256;
    u16* obase = Y + (size_t)(e * CAP + base) * NH + n0;
    #pragma unroll
    for (int i = 0; i < 8; ++i) {
      int task = i * 256 + t;
      int r = task >> 3, p = task & 7;
      if (r < rmax) {
        bf16x8 v = *(const bf16x8*)(lds + r * 128 + ((p * 16) ^ ((r & 7) << 4)));
        *(bf16x8*)(obase + (size_t)r * NH + p * 8) = v;
      }
    }
  }
}

// ---------------- combine ----------------
__global__ void k_combine(const int* __restrict__ slot_of_pair, const float* __restrict__ wts,
                          const u16* __restrict__ Y, float* __restrict__ out)
{
  int t = threadIdx.x;
  int tok = blockIdx.x * 2 + (t >> 7);
  int c = t & 127;
  f32x4 a = (f32x4){0.f, 0.f, 0.f, 0.f};
  #pragma unroll
  for (int k = 0; k < NKK; ++k) {
    int n = tok * NKK + k;
    int s = slot_of_pair[n];
    if (s >= 0) {
      float wv = wts[n];
      s16x4 y = *(const s16x4*)(Y + (size_t)s * NH + c * 4);
      a[0] += wv * bf2f(y[0]);
      a[1] += wv * bf2f(y[1]);
      a[2] += wv * bf2f(y[2]);
      a[3] += wv * bf2f(y[3]);
    }
  }
  *(f32x4*)(out + (size_t)tok * NH + c * 4) = a;
  *(f32x4*)(out + (size_t)(NT + tok) * NH + c * 4) = a;
}

extern "C" void kernel_launch(void* const* d_in, const int* in_sizes, int n_in,
                              void* d_out, int out_size, void* d_ws, size_t ws_size,
                              hipStream_t stream) {
  const float* hid  = (const float*)d_in[0];
  const int*   topk = (const int*)d_in[1];
  const float* wts  = (const float*)d_in[2];
  const float* wgu  = (const float*)d_in[3];
  const float* wdn  = (const float*)d_in[4];

  char* ws = (char*)d_ws;
  size_t off = 0;
  auto alloc = [&](size_t sz) { char* p = ws + off; off = (off + sz + 255) & ~(size_t)255; return p; };
  int* counts        = (int*)alloc(NE * 4);
  int* slot_of_pair  = (int*)alloc((size_t)NPAIR * 4);
  int* pair_of_slot  = (int*)alloc((size_t)NE * CAP * 4);
  u16* xbuf          = (u16*)alloc((size_t)NE * CAP * NH * 2);
  u16* Y             = (u16*)alloc((size_t)NE * CAP * NH * 2);
  size_t remain = ws_size > off ? ws_size - off : 0;
  size_t per_e = (size_t)CAP * NI * 2;
  int chunkE = (int)(remain / per_e);
  if (chunkE > NE) chunkE = NE;
  if (chunkE < 1) chunkE = 1;
  u16* inter = (u16*)(ws + off);

  hipMemsetAsync(counts, 0, NE * 4, stream);
  k_route<<<NPAIR / 256, 256, 0, stream>>>(topk, counts, slot_of_pair, pair_of_slot);
  k_gather<<<NE * CAP / 2, 256, 0, stream>>>(hid, counts, pair_of_slot, xbuf);
  for (int e0 = 0; e0 < NE; e0 += chunkE) {
    int ce = NE - e0 < chunkE ? NE - e0 : chunkE;
    int nb1 = ce * 58;
    int nb2 = ce * 8;
    k_gemm1<<<nb1, 256, 0, stream>>>(xbuf, wgu, counts, inter, e0, nb1);
    k_gemm2<<<nb2, 256, 0, stream>>>(inter, wdn, counts, Y, e0, nb2);
  }
  k_combine<<<NT / 2, 256, 0, stream>>>(slot_of_pair, wts, Y, (float*)d_out);
}